// Round 18
// baseline (155.037 us; speedup 1.0000x reference)
//
#include <hip/hip_runtime.h>

#define IH 512
#define IW 512
#define OH 510
#define OW 510
#define NB 32
#define KO 16
#define OHW (OH * OW)
#define PPB 8              // planes per block (o-half)

typedef float f32x4 __attribute__((ext_vector_type(4)));
typedef float f32x2 __attribute__((ext_vector_type(2)));

// R18: A/B against R15 — same tile/thread mapping (4 cols x 1 row x 8 planes,
// wave-contiguous 16B-aligned stores both parities), but DIRECT stores from
// accumulators (no LDS bounce, no __syncthreads, no idle tail in store phase).
// Tests whether R12's +20% was the LDS bounce itself or just {burst stores +
// PPB 16->8}. If this matches/beats 118.4, bounce was overhead; if >=130,
// the bounce's store-burst decoupling is load-bearing -> revert to R15.
__global__ __launch_bounds__(256, 4) void conv3x3_k16_kernel(
    const float* __restrict__ x,
    const float* __restrict__ k,
    float* __restrict__ out)
{
    const int bid  = blockIdx.x;
    const int oh   = bid & 1;                 // filter half: planes 8*oh..
    const int tile = bid >> 1;
    const int n  = tile / (OH / 2);           // image
    const int i0 = (tile - n * (OH / 2)) * 2; // even base row
    const int t  = threadIdx.x;
    const int half = t >> 7;                  // row within pair
    const int tt = t & 127;
    const int i  = i0 + half;                 // output row
    const bool tail = (tt == 127);

    // Even rows: j=4tt (tail 508); odd rows: j=4tt+2 (tail 0).
    int j;
    if ((i & 1) == 0) j = tail ? 508 : 4 * tt;
    else              j = tail ? 0   : 4 * tt + 2;

    const float* xr = x + ((size_t)n * IH + i) * IW + j;

    // Phase 1: load 3 rows x 6 cols (tail: 3 x 4), 8B-aligned float2s.
    float xv[3][6];
#pragma unroll
    for (int r = 0; r < 3; ++r) {
        const float2 a = *reinterpret_cast<const float2*>(xr + r * IW);
        const float2 b = *reinterpret_cast<const float2*>(xr + r * IW + 2);
        xv[r][0] = a.x; xv[r][1] = a.y; xv[r][2] = b.x; xv[r][3] = b.y;
        if (!tail) {
            const float2 c = *reinterpret_cast<const float2*>(xr + r * IW + 4);
            xv[r][4] = c.x; xv[r][5] = c.y;
        } else {
            xv[r][4] = 0.0f; xv[r][5] = 0.0f;
        }
    }

    // Phase 2: compute all 8x4 accumulators (32 distinct VGPRs).
    float acc[PPB][4];
#pragma unroll
    for (int ol = 0; ol < PPB; ++ol) {
        const int o = PPB * oh + ol;
        float a0 = 0.f, a1 = 0.f, a2 = 0.f, a3 = 0.f;
#pragma unroll
        for (int r = 0; r < 3; ++r)
#pragma unroll
            for (int c = 0; c < 3; ++c) {
                const float kv = k[(o * 3 + r) * 3 + c];  // uniform -> s_load
                a0 = fmaf(xv[r][c],     kv, a0);
                a1 = fmaf(xv[r][c + 1], kv, a1);
                a2 = fmaf(xv[r][c + 2], kv, a2);
                a3 = fmaf(xv[r][c + 3], kv, a3);
            }
        acc[ol][0] = a0; acc[ol][1] = a1; acc[ol][2] = a2; acc[ol][3] = a3;
    }

    __builtin_amdgcn_sched_barrier(0);

    // Phase 3: 8 back-to-back plain stores (wave-contiguous, 16B-aligned).
    float* ob = out + (((size_t)(n * KO + PPB * oh)) * OH + i) * OW + j;
#pragma unroll
    for (int ol = 0; ol < PPB; ++ol) {
        float* p = ob + (size_t)ol * OHW;
        if (!tail) {
            f32x4 v; v[0] = acc[ol][0]; v[1] = acc[ol][1];
                     v[2] = acc[ol][2]; v[3] = acc[ol][3];
            *reinterpret_cast<f32x4*>(p) = v;
        } else {
            f32x2 v; v[0] = acc[ol][0]; v[1] = acc[ol][1];
            *reinterpret_cast<f32x2*>(p) = v;
        }
    }
}

extern "C" void kernel_launch(void* const* d_in, const int* in_sizes, int n_in,
                              void* d_out, int out_size, void* d_ws, size_t ws_size,
                              hipStream_t stream) {
    const float* x   = (const float*)d_in[0];
    const float* ker = (const float*)d_in[1];
    float* out       = (float*)d_out;

    dim3 grid(NB * (OH / 2) * 2);   // 16320 blocks: (image, row-pair) x o-half
    dim3 block(256);
    conv3x3_k16_kernel<<<grid, block, 0, stream>>>(x, ker, out);
}

// Round 19
// 120.233 us; speedup vs baseline: 1.2895x; 1.2895x over previous
//
#include <hip/hip_runtime.h>

#define IH 512
#define IW 512
#define OH 510
#define OW 510
#define NB 32
#define KO 16
#define OHW (OH * OW)
#define PPB 8              // planes per block (o-half)
#define LO 1020            // floats per plane-region in LDS (2 rows x 510)
#define TPB 3              // row-pair tiles per block (85 * 3 = 255)
#define NQP 85

typedef float f32x4 __attribute__((ext_vector_type(4)));
typedef float f32x2 __attribute__((ext_vector_type(2)));

// R19 = R15's proven structure (LDS-bounce drain, plain stores, PPB=8)
// pipelined over 3 tiles with loads hoisted a full phase early:
//   load A,B; FMA A->b0; S; {load C, drain A, FMA B->b1}; S;
//   {drain B, FMA C->b0}; S; drain C.
// __syncthreads' vmcnt(0) always finds the next tile's loads already
// complete (issued one phase ahead), so the cold-load head that every R15
// generation paid is amortized 3x; drain(t) issues before FMA(t+1) so
// stores flow during compute. Double-buffered LDS 65.3KB -> 2 blocks/CU.

__device__ __forceinline__ void load_xv(const float* __restrict__ xr,
                                        bool tail, float v[3][6])
{
#pragma unroll
    for (int r = 0; r < 3; ++r) {
        const float2 a = *reinterpret_cast<const float2*>(xr + r * IW);
        const float2 b = *reinterpret_cast<const float2*>(xr + r * IW + 2);
        v[r][0] = a.x; v[r][1] = a.y; v[r][2] = b.x; v[r][3] = b.y;
        if (!tail) {
            const float2 c = *reinterpret_cast<const float2*>(xr + r * IW + 4);
            v[r][4] = c.x; v[r][5] = c.y;
        } else {
            v[r][4] = 0.0f; v[r][5] = 0.0f;
        }
    }
}

__device__ __forceinline__ void fma_to_lds(const float xv[3][6],
                                           const float* __restrict__ k,
                                           int ob, float* __restrict__ buf,
                                           int lbase, bool tail)
{
#pragma unroll
    for (int ol = 0; ol < PPB; ++ol) {
        const int o = ob + ol;
        float a0 = 0.f, a1 = 0.f, a2 = 0.f, a3 = 0.f;
#pragma unroll
        for (int r = 0; r < 3; ++r)
#pragma unroll
            for (int c = 0; c < 3; ++c) {
                const float kv = k[(o * 3 + r) * 3 + c];  // uniform -> s_load
                a0 = fmaf(xv[r][c],     kv, a0);
                a1 = fmaf(xv[r][c + 1], kv, a1);
                a2 = fmaf(xv[r][c + 2], kv, a2);
                a3 = fmaf(xv[r][c + 3], kv, a3);
            }
        float* lp = buf + ol * LO + lbase;
        f32x2 v0; v0[0] = a0; v0[1] = a1;
        *reinterpret_cast<f32x2*>(lp) = v0;
        if (!tail) {
            f32x2 v1; v1[0] = a2; v1[1] = a3;
            *reinterpret_cast<f32x2*>(lp + 2) = v1;
        }
    }
}

__device__ __forceinline__ void drain(const float* __restrict__ buf,
                                      float* __restrict__ on, int rp,
                                      int f, bool active)
{
    if (active) {
        float* ob = on + (size_t)(2 * rp) * OW;
#pragma unroll
        for (int ol = 0; ol < PPB; ++ol) {
            const f32x4 v = *reinterpret_cast<const f32x4*>(buf + ol * LO + f);
            *reinterpret_cast<f32x4*>(ob + (size_t)ol * OHW + f) = v;
        }
    }
}

__global__ __launch_bounds__(256, 2) void conv3x3_k16_kernel(
    const float* __restrict__ x,
    const float* __restrict__ k,
    float* __restrict__ out)
{
    __shared__ float lds[2][PPB * LO];   // 65,280 B -> 2 blocks/CU

    const int bid  = blockIdx.x;
    const int oh   = bid & 1;
    const int rest = bid >> 1;
    const int qp   = rest % NQP;
    const int n    = rest / NQP;
    const int rp0  = qp * TPB;

    const int t    = threadIdx.x;
    const int half = t >> 7;
    const int tt   = t & 127;
    const bool tail = (tt == 127);

    // Even rows: j=4tt (tail 508); odd rows: j=4tt+2 (tail 0).
    // Row parity == half parity for every tile (rows 2*rp + half).
    int j;
    if (half == 0) j = tail ? 508 : 4 * tt;
    else           j = tail ? 0   : 4 * tt + 2;
    const int lbase = half * OW + j;
    const int f = 4 * t;
    const bool active = (t < 255);
    const int ob_f = PPB * oh;

    const float* xn = x + (size_t)n * IH * IW;
    float* on = out + (size_t)(n * KO + ob_f) * OHW;

    float xvA[3][6], xvB[3][6];
    // Prologue: both tile 0 and tile 1 loads in flight from the start.
    load_xv(xn + (size_t)(2 * rp0 + half) * IW + j, tail, xvA);
    load_xv(xn + (size_t)(2 * (rp0 + 1) + half) * IW + j, tail, xvB);

    // Phase 1: tile 0 compute.
    fma_to_lds(xvA, k, ob_f, &lds[0][0], lbase, tail);
    __syncthreads();

    // Phase 2: tile 2 loads issue, tile 0 drains, tile 1 computes.
    load_xv(xn + (size_t)(2 * (rp0 + 2) + half) * IW + j, tail, xvA);
    drain(&lds[0][0], on, rp0, f, active);
    fma_to_lds(xvB, k, ob_f, &lds[1][0], lbase, tail);
    __syncthreads();

    // Phase 3: tile 1 drains, tile 2 computes.
    drain(&lds[1][0], on, rp0 + 1, f, active);
    fma_to_lds(xvA, k, ob_f, &lds[0][0], lbase, tail);
    __syncthreads();

    // Epilogue: tile 2 drains.
    drain(&lds[0][0], on, rp0 + 2, f, active);
}

extern "C" void kernel_launch(void* const* d_in, const int* in_sizes, int n_in,
                              void* d_out, int out_size, void* d_ws, size_t ws_size,
                              hipStream_t stream) {
    const float* x   = (const float*)d_in[0];
    const float* ker = (const float*)d_in[1];
    float* out       = (float*)d_out;

    dim3 grid(NB * NQP * 2);   // 5440 blocks: (n, row-triple) x o-half
    dim3 block(256);
    conv3x3_k16_kernel<<<grid, block, 0, stream>>>(x, ker, out);
}

// Round 20
// 119.164 us; speedup vs baseline: 1.3010x; 1.0090x over previous
//
#include <hip/hip_runtime.h>

#define IH 512
#define IW 512
#define OH 510
#define OW 510
#define NB 32
#define KO 16
#define OHW (OH * OW)
#define PPB 8              // planes per block (o-half)
#define LO 1024            // padded plane stride in LDS (floats); 1020 used

typedef float f32x4 __attribute__((ext_vector_type(4)));
typedef float f32x2 __attribute__((ext_vector_type(2)));

// R20 = R15 (champion 118.4us) with ONE change: monotonic per-wave drain.
// R15's drain: each wave's 8 successive stores hit 8 planes ~1MB apart
// (fan-out 8, each region revisited per instruction). R20: thread t owns
// plane t>>5, chunk t&31 -> each wave drains only 2 planes, walking each
// window SEQUENTIALLY (8 rounds x 512B contiguous per plane per instr,
// 4 full 128B lines per segment, successive rounds adjoin -> fill-like
// monotonic streams at wave granularity). Compute phase byte-identical.
__global__ __launch_bounds__(256, 4) void conv3x3_k16_kernel(
    const float* __restrict__ x,
    const float* __restrict__ k,
    float* __restrict__ out)
{
    __shared__ float lds[PPB * LO];   // 32,768 B -> 4 blocks/CU

    const int bid  = blockIdx.x;
    const int oh   = bid & 1;                 // filter half: planes 8*oh..
    const int tile = bid >> 1;
    const int n  = tile / (OH / 2);           // image
    const int i0 = (tile - n * (OH / 2)) * 2; // even base row
    const int t  = threadIdx.x;
    const int half = t >> 7;                  // row within pair
    const int tt = t & 127;
    const int i  = i0 + half;                 // output row
    const bool tail = (tt == 127);

    // Even rows: j=4tt (tail 508); odd rows: j=4tt+2 (tail 0).
    int j;
    if ((i & 1) == 0) j = tail ? 508 : 4 * tt;
    else              j = tail ? 0   : 4 * tt + 2;

    const float* xr = x + ((size_t)n * IH + i) * IW + j;

    // Phase 1: load 3 rows x 6 cols (tail: 3 x 4), 8B-aligned float2s.
    float xv[3][6];
#pragma unroll
    for (int r = 0; r < 3; ++r) {
        const float2 a = *reinterpret_cast<const float2*>(xr + r * IW);
        const float2 b = *reinterpret_cast<const float2*>(xr + r * IW + 2);
        xv[r][0] = a.x; xv[r][1] = a.y; xv[r][2] = b.x; xv[r][3] = b.y;
        if (!tail) {
            const float2 c = *reinterpret_cast<const float2*>(xr + r * IW + 4);
            xv[r][4] = c.x; xv[r][5] = c.y;
        } else {
            xv[r][4] = 0.0f; xv[r][5] = 0.0f;
        }
    }

    // Phase 2: FMA for 8 planes, deposit into LDS (row-pair flat layout:
    // flat = half*510 + col, plane stride LO=1024 floats).
    const int lbase = half * OW + j;
#pragma unroll
    for (int ol = 0; ol < PPB; ++ol) {
        const int o = PPB * oh + ol;
        float a0 = 0.f, a1 = 0.f, a2 = 0.f, a3 = 0.f;
#pragma unroll
        for (int r = 0; r < 3; ++r)
#pragma unroll
            for (int c = 0; c < 3; ++c) {
                const float kv = k[(o * 3 + r) * 3 + c];  // uniform -> s_load
                a0 = fmaf(xv[r][c],     kv, a0);
                a1 = fmaf(xv[r][c + 1], kv, a1);
                a2 = fmaf(xv[r][c + 2], kv, a2);
                a3 = fmaf(xv[r][c + 3], kv, a3);
            }
        float* lp = &lds[ol * LO + lbase];
        f32x2 v0; v0[0] = a0; v0[1] = a1;
        *reinterpret_cast<f32x2*>(lp) = v0;
        if (!tail) {
            f32x2 v1; v1[0] = a2; v1[1] = a3;
            *reinterpret_cast<f32x2*>(lp + 2) = v1;
        }
    }

    __syncthreads();

    // Phase 3: monotonic drain. Thread t -> plane p = t>>5, lane-chunk
    // l = t&31. 8 rounds; round q stores 16B at float-offset q*128 + 4l
    // (512B contiguous per plane per round; rounds adjoin). Window is
    // 1020 floats -> skip the single l=31,q=7 overhang.
    {
        const int p = t >> 5;
        const int l = t & 31;
        float* ob = out + (((size_t)(n * KO + PPB * oh + p)) * OH + i0) * OW;
        const float* lp = &lds[p * LO];
#pragma unroll
        for (int q = 0; q < 8; ++q) {
            const int fo = q * 128 + 4 * l;
            if (fo < 1020) {
                const f32x4 v = *reinterpret_cast<const f32x4*>(lp + fo);
                *reinterpret_cast<f32x4*>(ob + fo) = v;
            }
        }
    }
}

extern "C" void kernel_launch(void* const* d_in, const int* in_sizes, int n_in,
                              void* d_out, int out_size, void* d_ws, size_t ws_size,
                              hipStream_t stream) {
    const float* x   = (const float*)d_in[0];
    const float* ker = (const float*)d_in[1];
    float* out       = (float*)d_out;

    dim3 grid(NB * (OH / 2) * 2);   // 16320 blocks: (image, row-pair) x o-half
    dim3 block(256);
    conv3x3_k16_kernel<<<grid, block, 0, stream>>>(x, ker, out);
}